// Round 6
// baseline (369.657 us; speedup 1.0000x reference)
//
#include <hip/hip_runtime.h>
#include <math.h>

// ---------------------------------------------------------------------------
// Fastformer encoder layer — Round 13: R12 structure, validated sync (bisect).
//
// R12 post-mortem: absmax 0.535 — moderate, race-like. Addressing re-derived
// 3x identical to R7-validated formulas; the only unvalidated deltas were
// BM=256 scaling and raw-barrier+vmcnt(4) coexisting with compiler-managed
// B-register loads. R13 keeps the structural win (B direct-to-reg fragment-
// linear weights -> LDS read/tile halved, A-only dbuf 64/32KB -> 2-3
// blocks/CU co-resident; m114 overlap covers the drain) and restores the
// R7-validated full __syncthreads() per K-tile. If this passes, R12's bug
// was the counted-vmcnt window; if it fails, BM=256 addressing is at fault.
//  * fgemm5: BM=256 (kv, lin1: wave 128x64, acc[8][4]) | BM=128 (out, lin2:
//    wave 64x64, acc[4][4], = R7's validated fgemm verbatim + setprio).
//  * loop: [LB b1][SGA next][ks0 MFMA b0][LB b0 next][ks1 MFMA b1][sync].
// ws: h16@0 | kv16/act16@16M | vq@48M | sw weights@64M | gk@82M | attn@83M
// ---------------------------------------------------------------------------

#define DM     1024
#define FFH    2048
#define M_TOT  8192

typedef _Float16 f16x8 __attribute__((ext_vector_type(8)));
typedef float    f32x4 __attribute__((ext_vector_type(4)));

__device__ __forceinline__ void gl2lds16(const void* g, void* l) {
    __builtin_amdgcn_global_load_lds(
        (const __attribute__((address_space(1))) void*)g,
        (__attribute__((address_space(3))) void*)l, 16, 0, 0);
}
__device__ __forceinline__ unsigned short f2h(float x) {
    union { _Float16 h; unsigned short u; } c;
    c.h = (_Float16)x;
    return c.u;
}
__device__ __forceinline__ float h2f(unsigned short u) {
    union { unsigned short u; _Float16 h; } c;
    c.u = u;
    return (float)c.h;
}

// ---------------------------------------------------------------------------
// weight cast fp32 -> fp16 in fragment-linear layout (validated R6/R7):
// chunk i = (ntile*KT32 + kt)*64 + lane ; holds
// W[nt*16 + (lane&15)][kt*32 + (lane>>4)*8 .. +8].
// ---------------------------------------------------------------------------
__global__ __launch_bounds__(256) void wcast_sw(
    const float* __restrict__ s0, const float* __restrict__ s1,
    const float* __restrict__ s2, const float* __restrict__ s3,
    unsigned short* __restrict__ d0, unsigned short* __restrict__ d1,
    unsigned short* __restrict__ d2, unsigned short* __restrict__ d3)
{
    int i = blockIdx.x * 256 + threadIdx.x;
    const float* s; unsigned short* d; int ks;
    if      (i < 262144) {               s = s0; d = d0; ks = 5; }
    else if (i < 393216) { i -= 262144;  s = s1; d = d1; ks = 5; }
    else if (i < 917504) { i -= 393216;  s = s2; d = d2; ks = 5; }
    else                 { i -= 917504;  s = s3; d = d3; ks = 6; }
    const int lane = i & 63, tile = i >> 6;
    const int kt = tile & ((1 << ks) - 1), nt = tile >> ks;
    const int fr = lane & 15, qq = lane >> 4;
    const int K = 32 << ks;
    const float* src = s + (size_t)(nt * 16 + fr) * K + kt * 32 + qq * 8;
    const float4 v0 = ((const float4*)src)[0];
    const float4 v1 = ((const float4*)src)[1];
    ushort4 h0, h1;
    h0.x = f2h(v0.x); h0.y = f2h(v0.y); h0.z = f2h(v0.z); h0.w = f2h(v0.w);
    h1.x = f2h(v1.x); h1.y = f2h(v1.y); h1.z = f2h(v1.z); h1.w = f2h(v1.w);
    unsigned short* dst = d + (size_t)i * 8;
    *(ushort4*)dst       = h0;
    *(ushort4*)(dst + 4) = h1;
}

// ---------------------------------------------------------------------------
// LayerNorm -> fp16. One block/row, one float4/thread.
// ---------------------------------------------------------------------------
__global__ __launch_bounds__(256) void ln_f16(
    const float* __restrict__ x, const float* __restrict__ g,
    const float* __restrict__ b, unsigned short* __restrict__ y)
{
    const int row = blockIdx.x;
    const int t   = threadIdx.x;
    const float4 v = ((const float4*)(x + (size_t)row * DM))[t];

    float s  = v.x + v.y + v.z + v.w;
    float ss = v.x * v.x + v.y * v.y + v.z * v.z + v.w * v.w;
    #pragma unroll
    for (int off = 32; off > 0; off >>= 1) {
        s  += __shfl_xor(s, off);
        ss += __shfl_xor(ss, off);
    }
    __shared__ float sm[8];
    const int wave = t >> 6;
    if ((t & 63) == 0) { sm[wave * 2] = s; sm[wave * 2 + 1] = ss; }
    __syncthreads();
    s  = sm[0] + sm[2] + sm[4] + sm[6];
    ss = sm[1] + sm[3] + sm[5] + sm[7];

    const float mu  = s * (1.0f / DM);
    const float var = ss * (1.0f / DM) - mu * mu;
    const float r   = rsqrtf(var + 1e-5f);

    const float4 gv = ((const float4*)g)[t];
    const float4 bv = ((const float4*)b)[t];
    ushort4 o;
    o.x = f2h((v.x - mu) * r * gv.x + bv.x);
    o.y = f2h((v.y - mu) * r * gv.y + bv.y);
    o.z = f2h((v.z - mu) * r * gv.z + bv.z);
    o.w = f2h((v.w - mu) * r * gv.w + bv.w);
    ((ushort4*)(y + (size_t)row * DM))[t] = o;
}

// ---------------------------------------------------------------------------
// attention partial pass + merge (verified R4-R12, unchanged).
// ---------------------------------------------------------------------------
__global__ __launch_bounds__(256) void attn_part(
    const unsigned short* __restrict__ kv, const float* __restrict__ kw,
    float* __restrict__ pm, float* __restrict__ pl, float* __restrict__ ps)
{
    const int blk = blockIdx.x;
    const int bh = blk >> 2, qt = blk & 3;
    const int b = bh >> 4, h = bh & 15;
    const int t = threadIdx.x, e = t & 63, w = t >> 6;
    const int nbase = qt * 256 + w * 64;
    const unsigned short* kp =
        kv + (size_t)b * 1024 * 2048 + (size_t)nbase * 2048 + h * 64 + e;
    const float* kwr = kw + h * 1024 + nbase;

    float m = -1e30f, l = 0.f, s = 0.f;
    #pragma unroll 4
    for (int i = 0; i < 64; ++i) {
        const float kval = h2f(kp[(size_t)i * 2048]);
        const float x    = kval * kwr[i] * 0.125f;
        const float nm   = fmaxf(m, x);
        const float c    = __expf(m - nm);
        const float ex   = __expf(x - nm);
        l = l * c + ex;
        s = s * c + ex * kval;
        m = nm;
    }
    __shared__ float sm[3][256];
    sm[0][t] = m; sm[1][t] = l; sm[2][t] = s;
    __syncthreads();
    if (t < 64) {
        #pragma unroll
        for (int ww = 1; ww < 4; ++ww) {
            const float m2 = sm[0][ww * 64 + e];
            const float l2 = sm[1][ww * 64 + e];
            const float s2 = sm[2][ww * 64 + e];
            const float nm = fmaxf(m, m2);
            const float c1 = __expf(m - nm);
            const float c2 = __expf(m2 - nm);
            l = l * c1 + l2 * c2;
            s = s * c1 + s2 * c2;
            m = nm;
        }
        const int o = blk * 64 + e;
        pm[o] = m; pl[o] = l; ps[o] = s;
    }
}

__global__ __launch_bounds__(64) void attn_merge(
    const float* __restrict__ pm, const float* __restrict__ pl,
    const float* __restrict__ ps, float* __restrict__ gk)
{
    const int bh = blockIdx.x, e = threadIdx.x;
    const int b = bh >> 4, h = bh & 15;
    int o = bh * 4 * 64 + e;
    float m = pm[o], l = pl[o], s = ps[o];
    #pragma unroll
    for (int qt = 1; qt < 4; ++qt) {
        o += 64;
        const float m2 = pm[o], l2 = pl[o], s2 = ps[o];
        const float nm = fmaxf(m, m2);
        const float c1 = __expf(m - nm);
        const float c2 = __expf(m2 - nm);
        l = l * c1 + l2 * c2;
        s = s * c1 + s2 * c2;
        m = nm;
    }
    gk[(size_t)b * DM + h * 64 + e] = s / l;
}

// ---------------------------------------------------------------------------
// v-scale: vq[m][d] = fp16( v16[m][d] * gk[batch][d] ).
// ---------------------------------------------------------------------------
__global__ __launch_bounds__(256) void vscale_f16(
    const unsigned short* __restrict__ kv, const float* __restrict__ gk,
    unsigned short* __restrict__ vq)
{
    const int m = blockIdx.x;
    const int t = threadIdx.x;
    const int b = m >> 10;
    const ushort4 v4 = *(const ushort4*)(kv + (size_t)m * 2048 + 1024 + t * 4);
    const float4  s4 = *(const float4*)(gk + b * DM + t * 4);
    ushort4 o;
    o.x = f2h(h2f(v4.x) * s4.x);
    o.y = f2h(h2f(v4.y) * s4.y);
    o.z = f2h(h2f(v4.z) * s4.z);
    o.w = f2h(h2f(v4.w) * s4.w);
    *(ushort4*)(vq + (size_t)m * DM + t * 4) = o;
}

// ---------------------------------------------------------------------------
// fp16 MFMA GEMM. 256 thr = 4 waves (2 wm x 2 wn), block tile BM x 128
// (LIN1ACT: BM x 64 product cols; wn=0 a-half, wn=1 g-half).
// Wave tile = (BM/2) x 64. acc[MR][4], MR = BM/32.
// A staged via gl2lds, 2-slot dbuf (LDS 64KB/32KB -> 2-3 blocks/CU).
// B direct-to-register from fragment-linear weights (wcast_sw layout).
// Sync: full __syncthreads() once per K-tile (R7-validated discipline).
// OUTM: 0 fp16 out, 2 fp32 out + residual.
// ---------------------------------------------------------------------------
template <bool LIN1ACT, int OUTM, int BM>
__global__ __launch_bounds__(256, BM == 256 ? 2 : 3) void fgemm5(
    const unsigned short* __restrict__ A,
    const unsigned short* __restrict__ Bsw,
    const float* __restrict__ bias,
    const float* __restrict__ residual,
    float* __restrict__ Cf, unsigned short* __restrict__ Cq,
    int K, int lda, int ldc)
{
    constexpr int WROWS = BM / 2;          // 128 | 64
    constexpr int MR    = WROWS / 16;      // 8 | 4
    constexpr int MH    = MR / 4;          // 2 | 1
    constexpr int ASLAB = BM * 128;        // 32768 | 16384
    constexpr int AEV   = ASLAB / 4096;    // 8 | 4
    __shared__ __align__(16) char lds[2 * ASLAB];

    const int t   = threadIdx.x;
    const int wid = t >> 6, L = t & 63;
    const int wm  = wid >> 1, wn = wid & 1;
    const int fr  = L & 15, q = L >> 4;
    const int m0  = blockIdx.y * BM;
    const int n0  = blockIdx.x * (LIN1ACT ? 64 : 128);
    const int KT32 = K >> 5;

    // A staging (validated layout): event = 32 rows; thread t covers
    // row j*32 + (t>>3), LDS chunk t&7 holds source chunk (t&7)^(row&7).
    const int srow = t >> 3;
    const int sch  = (t & 7) ^ (srow & 7);
    const unsigned short* pA = A + (size_t)(m0 + srow) * lda + sch * 8;

    // B fragment-linear base for this wave's 64 cols.
    const int ct0 = LIN1ACT ? ((wn ? (FFH + n0) : n0) >> 4)
                            : ((n0 + wn * 64) >> 4);
    const unsigned short* pB = Bsw + (size_t)ct0 * KT32 * 512 + L * 8;

    int aoff[MR];
    #pragma unroll
    for (int mi = 0; mi < MR; ++mi) {
        const int row = wm * WROWS + mi * 16 + fr;
        aoff[mi] = row * 128 + ((q ^ (row & 7)) << 4);
    }

    f32x4 acc[MR][4];
    #pragma unroll
    for (int i = 0; i < MR; ++i)
        #pragma unroll
        for (int j = 0; j < 4; ++j) acc[i][j] = (f32x4){0.f, 0.f, 0.f, 0.f};
    f16x8 av[4], b0[4], b1[4];

#define SGA(sl, ko) do {                                                      \
        _Pragma("unroll")                                                     \
        for (int j_ = 0; j_ < AEV; ++j_)                                      \
            gl2lds16(pA + (size_t)j_ * 32 * lda + (ko),                       \
                     lds + (sl) * ASLAB + j_ * 4096 + t * 16);                \
    } while (0)
#define LB(dst, kt) do {                                                      \
        _Pragma("unroll")                                                     \
        for (int n_ = 0; n_ < 4; ++n_)                                        \
            dst[n_] = *(const f16x8*)(pB + ((size_t)n_ * KT32 + (kt)) * 512); \
    } while (0)
#define RD4(sl, ks, mh) do {                                                  \
        const char* ab_ = lds + (sl) * ASLAB;                                 \
        _Pragma("unroll")                                                     \
        for (int r_ = 0; r_ < 4; ++r_)                                        \
            av[r_] = *(const f16x8*)(ab_ + (aoff[(mh) * 4 + r_] ^             \
                                            ((ks) * 64)));                    \
    } while (0)
#define MM16(mh, B) do {                                                      \
        __builtin_amdgcn_s_setprio(1);                                        \
        _Pragma("unroll")                                                     \
        for (int r_ = 0; r_ < 4; ++r_)                                        \
            _Pragma("unroll")                                                 \
            for (int n_ = 0; n_ < 4; ++n_)                                    \
                acc[(mh) * 4 + r_][n_] =                                      \
                    __builtin_amdgcn_mfma_f32_16x16x32_f16(                   \
                        av[r_], B[n_], acc[(mh) * 4 + r_][n_], 0, 0, 0);      \
        __builtin_amdgcn_s_setprio(0);                                        \
    } while (0)

    const int KTile = K >> 6;

    // prologue: stage A(T0) -> slot0, load b0 (kt 0); full-drain sync.
    SGA(0, 0);
    LB(b0, 0);
    __syncthreads();

    for (int T = 0; T < KTile; ++T) {
        const int  s  = T & 1, ns = s ^ 1;
        const bool pre = (T + 1 < KTile);
        LB(b1, 2 * T + 1);
        if (pre) SGA(ns, (T + 1) << 6);
        RD4(s, 0, 0); MM16(0, b0);
        if constexpr (MH == 2) { RD4(s, 0, 1); MM16(1, b0); }
        if (pre) LB(b0, 2 * T + 2);
        RD4(s, 1, 0); MM16(0, b1);
        if constexpr (MH == 2) { RD4(s, 1, 1); MM16(1, b1); }
        __syncthreads();   // validated full drain (vmcnt0+lgkmcnt0+barrier)
    }
#undef SGA
#undef LB
#undef RD4
#undef MM16

    if constexpr (!LIN1ACT) {
        #pragma unroll
        for (int mi = 0; mi < MR; ++mi)
            #pragma unroll
            for (int ni = 0; ni < 4; ++ni) {
                const int gcol = n0 + wn * 64 + ni * 16 + fr;
                const float bc = bias[gcol];
                #pragma unroll
                for (int r = 0; r < 4; ++r) {
                    const int grow = m0 + wm * WROWS + mi * 16 + q * 4 + r;
                    float v = acc[mi][ni][r] + bc;
                    if constexpr (OUTM == 2) {
                        v += residual[(size_t)grow * ldc + gcol];
                        Cf[(size_t)grow * ldc + gcol] = v;
                    } else {
                        Cq[(size_t)grow * ldc + gcol] = f2h(v);
                    }
                }
            }
    } else {
        // a*relu(g): wn=1 waves hold g-cols -> relu+bias -> xch; wn=0 hold
        // a-cols -> multiply, store. xch [BM][64] fp16 <= 32KB (slot0).
        unsigned short* xch = (unsigned short*)lds;
        if (wn == 1) {
            #pragma unroll
            for (int mi = 0; mi < MR; ++mi)
                #pragma unroll
                for (int ni = 0; ni < 4; ++ni) {
                    const int pc = ni * 16 + fr;
                    const float bg = bias[FFH + n0 + pc];
                    #pragma unroll
                    for (int r = 0; r < 4; ++r) {
                        const int row = wm * WROWS + mi * 16 + q * 4 + r;
                        xch[row * 64 + pc] =
                            f2h(fmaxf(acc[mi][ni][r] + bg, 0.f));
                    }
                }
        }
        __syncthreads();
        if (wn == 0) {
            #pragma unroll
            for (int mi = 0; mi < MR; ++mi)
                #pragma unroll
                for (int ni = 0; ni < 4; ++ni) {
                    const int pc = ni * 16 + fr;
                    const float ba = bias[n0 + pc];
                    #pragma unroll
                    for (int r = 0; r < 4; ++r) {
                        const int row = wm * WROWS + mi * 16 + q * 4 + r;
                        const float a = acc[mi][ni][r] + ba;
                        const float o = a * h2f(xch[row * 64 + pc]);
                        Cq[(size_t)(m0 + row) * FFH + n0 + pc] = f2h(o);
                    }
                }
        }
    }
}

// ---------------------------------------------------------------------------
extern "C" void kernel_launch(void* const* d_in, const int* in_sizes, int n_in,
                              void* d_out, int out_size, void* d_ws, size_t ws_size,
                              hipStream_t stream)
{
    const float* hidden = (const float*)d_in[0];
    const float* qkv_w  = (const float*)d_in[2];
    const float* qkv_b  = (const float*)d_in[3];
    const float* out_w  = (const float*)d_in[4];
    const float* out_b  = (const float*)d_in[5];
    const float* key_w  = (const float*)d_in[7];
    const float* n1g    = (const float*)d_in[8];
    const float* n1b    = (const float*)d_in[9];
    const float* n2g    = (const float*)d_in[10];
    const float* n2b    = (const float*)d_in[11];
    const float* l1w    = (const float*)d_in[12];
    const float* l1b    = (const float*)d_in[13];
    const float* l2w    = (const float*)d_in[14];
    const float* l2b    = (const float*)d_in[15];
    float* out = (float*)d_out;
    char*  wsb = (char*)d_ws;

    const size_t MB = 1u << 20;
    unsigned short* h16    = (unsigned short*)wsb;               // 16 MB
    unsigned short* kv16   = (unsigned short*)(wsb + 16 * MB);   // 32 MB
    unsigned short* act16  = (unsigned short*)(wsb + 16 * MB);   // overlay
    unsigned short* vq     = (unsigned short*)(wsb + 48 * MB);   // 16 MB
    unsigned short* wkv_sw = (unsigned short*)(wsb + 64 * MB);   // 4 MB
    unsigned short* wo_sw  = (unsigned short*)(wsb + 68 * MB);   // 2 MB
    unsigned short* l1_sw  = (unsigned short*)(wsb + 70 * MB);   // 8 MB
    unsigned short* l2_sw  = (unsigned short*)(wsb + 78 * MB);   // 4 MB
    float*          gk     = (float*)(wsb + 82 * MB);            // 32 KB
    float*          pm     = (float*)(wsb + 83 * MB);            // 128 KB
    float*          pl     = (float*)(wsb + 83 * MB + 131072);
    float*          ps     = (float*)(wsb + 83 * MB + 262144);

    // 0. weights -> fp16 fragment-linear layout
    wcast_sw<<<4608, 256, 0, stream>>>(
        qkv_w + (size_t)DM * DM, out_w, l1w, l2w,
        wkv_sw, wo_sw, l1_sw, l2_sw);

    // 1. h1 = LN1(hidden) -> fp16
    ln_f16<<<M_TOT, 256, 0, stream>>>(hidden, n1g, n1b, h16);

    // 2. kv16 = fp16( h1 @ Wkv^T + b )  (ldc 2048), 512 blocks
    fgemm5<false, 0, 256><<<dim3(16, 32), 256, 0, stream>>>(
        h16, wkv_sw, qkv_b + DM, nullptr, nullptr, kv16, 1024, 1024, 2048);

    // 3. global_key (partial + merge)
    attn_part<<<512, 256, 0, stream>>>(kv16, key_w, pm, pl, ps);
    attn_merge<<<128, 64, 0, stream>>>(pm, pl, ps, gk);

    // 4. vq = fp16(v * gk)
    vscale_f16<<<M_TOT, 256, 0, stream>>>(kv16, gk, vq);

    // 5. hidden2 = hidden + vq @ out_w^T + out_b -> d_out, 512 blocks
    fgemm5<false, 2, 128><<<dim3(8, 64), 256, 0, stream>>>(
        vq, wo_sw, out_b, hidden, out, nullptr, 1024, 1024, 1024);

    // 6. h2 = LN2(hidden2) -> fp16
    ln_f16<<<M_TOT, 256, 0, stream>>>(out, n2g, n2b, h16);

    // 7. act16 = fp16( (h2@W_a^T+b_a) * relu(h2@W_g^T+b_g) ), 1024 blocks
    fgemm5<true, 0, 256><<<dim3(32, 32), 256, 0, stream>>>(
        h16, l1_sw, l1b, nullptr, nullptr, act16, 1024, 1024, 0);

    // 8. out = hidden2 + act @ l2w^T + l2b (in-place residual), 512 blocks
    fgemm5<false, 2, 128><<<dim3(8, 64), 256, 0, stream>>>(
        act16, l2_sw, l2b, out, out, nullptr, 2048, 2048, 1024);
}

// Round 7
// 361.207 us; speedup vs baseline: 1.0234x; 1.0234x over previous
//
#include <hip/hip_runtime.h>
#include <math.h>

// ---------------------------------------------------------------------------
// Fastformer encoder layer — Round 14: consolidate. R13-validated GEMM core
// (B direct-to-reg fragment-linear, A-only gl2lds dbuf, full __syncthreads
// per K-tile) + two measured-gap fixes:
//  * wcast_cl: coalesced-READ fragment-linear weight cast (R12/R13's gather
//    version read 32B per 4KB region; this reads lane-contiguous and
//    scatter-writes 16B chunks). Mapping verified element-wise identical:
//    W[17][45] -> chunk 2129 under both formulas.
//  * XCD-chunked bijective blockIdx swizzle in fgemm5 (T1): all grids %8==0;
//    each XCD gets a contiguous raster chunk -> A-panels L2-resident.
//  * BM=128 instances: __launch_bounds__(256,2) (3 unreachable at 176 regs).
// ws: h16@0 | kv16/act16@16M | vq@48M | sw weights@64M | gk@82M | attn@83M
// ---------------------------------------------------------------------------

#define DM     1024
#define FFH    2048
#define M_TOT  8192

typedef _Float16 f16x8 __attribute__((ext_vector_type(8)));
typedef float    f32x4 __attribute__((ext_vector_type(4)));

__device__ __forceinline__ void gl2lds16(const void* g, void* l) {
    __builtin_amdgcn_global_load_lds(
        (const __attribute__((address_space(1))) void*)g,
        (__attribute__((address_space(3))) void*)l, 16, 0, 0);
}
__device__ __forceinline__ unsigned short f2h(float x) {
    union { _Float16 h; unsigned short u; } c;
    c.h = (_Float16)x;
    return c.u;
}
__device__ __forceinline__ float h2f(unsigned short u) {
    union { unsigned short u; _Float16 h; } c;
    c.u = u;
    return (float)c.h;
}

// ---------------------------------------------------------------------------
// weight cast fp32 -> fp16, fragment-linear output, COALESCED READS.
// Thread i handles source chunk i (8 consecutive floats of W row-major):
//   row = i / (K/8), c = i % (K/8), kt = c>>2, qq = c&3
//   dst chunk = ((row>>4)*KT + kt)*64 + qq*16 + (row&15),  KT = K/32.
// Dst chunk holds W[nt*16+fr][kt*32+qq*8 .. +8) == validated wcast_sw layout.
// ---------------------------------------------------------------------------
__global__ __launch_bounds__(256) void wcast_cl(
    const float* __restrict__ s0, const float* __restrict__ s1,
    const float* __restrict__ s2, const float* __restrict__ s3,
    unsigned short* __restrict__ d0, unsigned short* __restrict__ d1,
    unsigned short* __restrict__ d2, unsigned short* __restrict__ d3)
{
    int i = blockIdx.x * 256 + threadIdx.x;
    const float* s; unsigned short* d; int rsh, cmk, KT;
    if      (i < 262144) {               s = s0; d = d0; rsh = 7; cmk = 127; KT = 32; }
    else if (i < 393216) { i -= 262144;  s = s1; d = d1; rsh = 7; cmk = 127; KT = 32; }
    else if (i < 917504) { i -= 393216;  s = s2; d = d2; rsh = 7; cmk = 127; KT = 32; }
    else                 { i -= 917504;  s = s3; d = d3; rsh = 8; cmk = 255; KT = 64; }
    const int row = i >> rsh, c = i & cmk;
    const int kt  = c >> 2,  qq = c & 3;
    const float4 v0 = ((const float4*)(s + (size_t)i * 8))[0];
    const float4 v1 = ((const float4*)(s + (size_t)i * 8))[1];
    ushort4 h0, h1;
    h0.x = f2h(v0.x); h0.y = f2h(v0.y); h0.z = f2h(v0.z); h0.w = f2h(v0.w);
    h1.x = f2h(v1.x); h1.y = f2h(v1.y); h1.z = f2h(v1.z); h1.w = f2h(v1.w);
    const size_t dch = ((size_t)(row >> 4) * KT + kt) * 64 + qq * 16 + (row & 15);
    unsigned short* dst = d + dch * 8;
    *(ushort4*)dst       = h0;
    *(ushort4*)(dst + 4) = h1;
}

// ---------------------------------------------------------------------------
// LayerNorm -> fp16. One block/row, one float4/thread.
// ---------------------------------------------------------------------------
__global__ __launch_bounds__(256) void ln_f16(
    const float* __restrict__ x, const float* __restrict__ g,
    const float* __restrict__ b, unsigned short* __restrict__ y)
{
    const int row = blockIdx.x;
    const int t   = threadIdx.x;
    const float4 v = ((const float4*)(x + (size_t)row * DM))[t];

    float s  = v.x + v.y + v.z + v.w;
    float ss = v.x * v.x + v.y * v.y + v.z * v.z + v.w * v.w;
    #pragma unroll
    for (int off = 32; off > 0; off >>= 1) {
        s  += __shfl_xor(s, off);
        ss += __shfl_xor(ss, off);
    }
    __shared__ float sm[8];
    const int wave = t >> 6;
    if ((t & 63) == 0) { sm[wave * 2] = s; sm[wave * 2 + 1] = ss; }
    __syncthreads();
    s  = sm[0] + sm[2] + sm[4] + sm[6];
    ss = sm[1] + sm[3] + sm[5] + sm[7];

    const float mu  = s * (1.0f / DM);
    const float var = ss * (1.0f / DM) - mu * mu;
    const float r   = rsqrtf(var + 1e-5f);

    const float4 gv = ((const float4*)g)[t];
    const float4 bv = ((const float4*)b)[t];
    ushort4 o;
    o.x = f2h((v.x - mu) * r * gv.x + bv.x);
    o.y = f2h((v.y - mu) * r * gv.y + bv.y);
    o.z = f2h((v.z - mu) * r * gv.z + bv.z);
    o.w = f2h((v.w - mu) * r * gv.w + bv.w);
    ((ushort4*)(y + (size_t)row * DM))[t] = o;
}

// ---------------------------------------------------------------------------
// attention partial pass + merge (verified R4-R13, unchanged).
// ---------------------------------------------------------------------------
__global__ __launch_bounds__(256) void attn_part(
    const unsigned short* __restrict__ kv, const float* __restrict__ kw,
    float* __restrict__ pm, float* __restrict__ pl, float* __restrict__ ps)
{
    const int blk = blockIdx.x;
    const int bh = blk >> 2, qt = blk & 3;
    const int b = bh >> 4, h = bh & 15;
    const int t = threadIdx.x, e = t & 63, w = t >> 6;
    const int nbase = qt * 256 + w * 64;
    const unsigned short* kp =
        kv + (size_t)b * 1024 * 2048 + (size_t)nbase * 2048 + h * 64 + e;
    const float* kwr = kw + h * 1024 + nbase;

    float m = -1e30f, l = 0.f, s = 0.f;
    #pragma unroll 4
    for (int i = 0; i < 64; ++i) {
        const float kval = h2f(kp[(size_t)i * 2048]);
        const float x    = kval * kwr[i] * 0.125f;
        const float nm   = fmaxf(m, x);
        const float c    = __expf(m - nm);
        const float ex   = __expf(x - nm);
        l = l * c + ex;
        s = s * c + ex * kval;
        m = nm;
    }
    __shared__ float sm[3][256];
    sm[0][t] = m; sm[1][t] = l; sm[2][t] = s;
    __syncthreads();
    if (t < 64) {
        #pragma unroll
        for (int ww = 1; ww < 4; ++ww) {
            const float m2 = sm[0][ww * 64 + e];
            const float l2 = sm[1][ww * 64 + e];
            const float s2 = sm[2][ww * 64 + e];
            const float nm = fmaxf(m, m2);
            const float c1 = __expf(m - nm);
            const float c2 = __expf(m2 - nm);
            l = l * c1 + l2 * c2;
            s = s * c1 + s2 * c2;
            m = nm;
        }
        const int o = blk * 64 + e;
        pm[o] = m; pl[o] = l; ps[o] = s;
    }
}

__global__ __launch_bounds__(64) void attn_merge(
    const float* __restrict__ pm, const float* __restrict__ pl,
    const float* __restrict__ ps, float* __restrict__ gk)
{
    const int bh = blockIdx.x, e = threadIdx.x;
    const int b = bh >> 4, h = bh & 15;
    int o = bh * 4 * 64 + e;
    float m = pm[o], l = pl[o], s = ps[o];
    #pragma unroll
    for (int qt = 1; qt < 4; ++qt) {
        o += 64;
        const float m2 = pm[o], l2 = pl[o], s2 = ps[o];
        const float nm = fmaxf(m, m2);
        const float c1 = __expf(m - nm);
        const float c2 = __expf(m2 - nm);
        l = l * c1 + l2 * c2;
        s = s * c1 + s2 * c2;
        m = nm;
    }
    gk[(size_t)b * DM + h * 64 + e] = s / l;
}

// ---------------------------------------------------------------------------
// v-scale: vq[m][d] = fp16( v16[m][d] * gk[batch][d] ).
// ---------------------------------------------------------------------------
__global__ __launch_bounds__(256) void vscale_f16(
    const unsigned short* __restrict__ kv, const float* __restrict__ gk,
    unsigned short* __restrict__ vq)
{
    const int m = blockIdx.x;
    const int t = threadIdx.x;
    const int b = m >> 10;
    const ushort4 v4 = *(const ushort4*)(kv + (size_t)m * 2048 + 1024 + t * 4);
    const float4  s4 = *(const float4*)(gk + b * DM + t * 4);
    ushort4 o;
    o.x = f2h(h2f(v4.x) * s4.x);
    o.y = f2h(h2f(v4.y) * s4.y);
    o.z = f2h(h2f(v4.z) * s4.z);
    o.w = f2h(h2f(v4.w) * s4.w);
    *(ushort4*)(vq + (size_t)m * DM + t * 4) = o;
}

// ---------------------------------------------------------------------------
// fp16 MFMA GEMM (R13-validated core). 256 thr = 4 waves (2 wm x 2 wn),
// block tile BM x 128 (LIN1ACT: BM x 64 product cols; wn=0 a, wn=1 g).
// Wave tile (BM/2) x 64, acc[MR][4]. A staged via gl2lds 2-slot dbuf
// (64/32KB). B direct-to-reg from fragment-linear weights. Full
// __syncthreads() per K-tile. NEW: XCD-chunked bijective blockIdx swizzle
// (grids are %8==0): swz=(orig&7)*(nwg/8)+(orig>>3) -> each XCD owns a
// contiguous raster chunk -> A-panels stay L2-resident.
// OUTM: 0 fp16 out, 2 fp32 out + residual.
// ---------------------------------------------------------------------------
template <bool LIN1ACT, int OUTM, int BM>
__global__ __launch_bounds__(256, 2) void fgemm5(
    const unsigned short* __restrict__ A,
    const unsigned short* __restrict__ Bsw,
    const float* __restrict__ bias,
    const float* __restrict__ residual,
    float* __restrict__ Cf, unsigned short* __restrict__ Cq,
    int K, int lda, int ldc)
{
    constexpr int WROWS = BM / 2;          // 128 | 64
    constexpr int MR    = WROWS / 16;      // 8 | 4
    constexpr int MH    = MR / 4;          // 2 | 1
    constexpr int ASLAB = BM * 128;        // 32768 | 16384
    constexpr int AEV   = ASLAB / 4096;    // 8 | 4
    __shared__ __align__(16) char lds[2 * ASLAB];

    const int t   = threadIdx.x;
    const int wid = t >> 6, L = t & 63;
    const int wm  = wid >> 1, wn = wid & 1;
    const int fr  = L & 15, q = L >> 4;

    // XCD-chunked bijective swizzle (nwg % 8 == 0 for all launches).
    const int gx   = gridDim.x;
    const int nwg  = gx * gridDim.y;
    const int orig = blockIdx.y * gx + blockIdx.x;
    const int swz  = (orig & 7) * (nwg >> 3) + (orig >> 3);
    const int bx   = swz % gx, by = swz / gx;

    const int m0  = by * BM;
    const int n0  = bx * (LIN1ACT ? 64 : 128);
    const int KT32 = K >> 5;

    // A staging (validated layout): event = 32 rows; thread t covers
    // row j*32 + (t>>3), LDS chunk t&7 holds source chunk (t&7)^(row&7).
    const int srow = t >> 3;
    const int sch  = (t & 7) ^ (srow & 7);
    const unsigned short* pA = A + (size_t)(m0 + srow) * lda + sch * 8;

    // B fragment-linear base for this wave's 64 cols.
    const int ct0 = LIN1ACT ? ((wn ? (FFH + n0) : n0) >> 4)
                            : ((n0 + wn * 64) >> 4);
    const unsigned short* pB = Bsw + (size_t)ct0 * KT32 * 512 + L * 8;

    int aoff[MR];
    #pragma unroll
    for (int mi = 0; mi < MR; ++mi) {
        const int row = wm * WROWS + mi * 16 + fr;
        aoff[mi] = row * 128 + ((q ^ (row & 7)) << 4);
    }

    f32x4 acc[MR][4];
    #pragma unroll
    for (int i = 0; i < MR; ++i)
        #pragma unroll
        for (int j = 0; j < 4; ++j) acc[i][j] = (f32x4){0.f, 0.f, 0.f, 0.f};
    f16x8 av[4], b0[4], b1[4];

#define SGA(sl, ko) do {                                                      \
        _Pragma("unroll")                                                     \
        for (int j_ = 0; j_ < AEV; ++j_)                                      \
            gl2lds16(pA + (size_t)j_ * 32 * lda + (ko),                       \
                     lds + (sl) * ASLAB + j_ * 4096 + t * 16);                \
    } while (0)
#define LB(dst, kt) do {                                                      \
        _Pragma("unroll")                                                     \
        for (int n_ = 0; n_ < 4; ++n_)                                        \
            dst[n_] = *(const f16x8*)(pB + ((size_t)n_ * KT32 + (kt)) * 512); \
    } while (0)
#define RD4(sl, ks, mh) do {                                                  \
        const char* ab_ = lds + (sl) * ASLAB;                                 \
        _Pragma("unroll")                                                     \
        for (int r_ = 0; r_ < 4; ++r_)                                        \
            av[r_] = *(const f16x8*)(ab_ + (aoff[(mh) * 4 + r_] ^             \
                                            ((ks) * 64)));                    \
    } while (0)
#define MM16(mh, B) do {                                                      \
        __builtin_amdgcn_s_setprio(1);                                        \
        _Pragma("unroll")                                                     \
        for (int r_ = 0; r_ < 4; ++r_)                                        \
            _Pragma("unroll")                                                 \
            for (int n_ = 0; n_ < 4; ++n_)                                    \
                acc[(mh) * 4 + r_][n_] =                                      \
                    __builtin_amdgcn_mfma_f32_16x16x32_f16(                   \
                        av[r_], B[n_], acc[(mh) * 4 + r_][n_], 0, 0, 0);      \
        __builtin_amdgcn_s_setprio(0);                                        \
    } while (0)

    const int KTile = K >> 6;

    // prologue: stage A(T0) -> slot0, load b0 (kt 0); full-drain sync.
    SGA(0, 0);
    LB(b0, 0);
    __syncthreads();

    for (int T = 0; T < KTile; ++T) {
        const int  s  = T & 1, ns = s ^ 1;
        const bool pre = (T + 1 < KTile);
        LB(b1, 2 * T + 1);
        if (pre) SGA(ns, (T + 1) << 6);
        RD4(s, 0, 0); MM16(0, b0);
        if constexpr (MH == 2) { RD4(s, 0, 1); MM16(1, b0); }
        if (pre) LB(b0, 2 * T + 2);
        RD4(s, 1, 0); MM16(0, b1);
        if constexpr (MH == 2) { RD4(s, 1, 1); MM16(1, b1); }
        __syncthreads();   // validated full drain (vmcnt0+lgkmcnt0+barrier)
    }
#undef SGA
#undef LB
#undef RD4
#undef MM16

    if constexpr (!LIN1ACT) {
        #pragma unroll
        for (int mi = 0; mi < MR; ++mi)
            #pragma unroll
            for (int ni = 0; ni < 4; ++ni) {
                const int gcol = n0 + wn * 64 + ni * 16 + fr;
                const float bc = bias[gcol];
                #pragma unroll
                for (int r = 0; r < 4; ++r) {
                    const int grow = m0 + wm * WROWS + mi * 16 + q * 4 + r;
                    float v = acc[mi][ni][r] + bc;
                    if constexpr (OUTM == 2) {
                        v += residual[(size_t)grow * ldc + gcol];
                        Cf[(size_t)grow * ldc + gcol] = v;
                    } else {
                        Cq[(size_t)grow * ldc + gcol] = f2h(v);
                    }
                }
            }
    } else {
        // a*relu(g): wn=1 waves hold g-cols -> relu+bias -> xch; wn=0 hold
        // a-cols -> multiply, store. xch [BM][64] fp16 <= 32KB (slot0).
        unsigned short* xch = (unsigned short*)lds;
        if (wn == 1) {
            #pragma unroll
            for (int mi = 0; mi < MR; ++mi)
                #pragma unroll
                for (int ni = 0; ni < 4; ++ni) {
                    const int pc = ni * 16 + fr;
                    const float bg = bias[FFH + n0 + pc];
                    #pragma unroll
                    for (int r = 0; r < 4; ++r) {
                        const int row = wm * WROWS + mi * 16 + q * 4 + r;
                        xch[row * 64 + pc] =
                            f2h(fmaxf(acc[mi][ni][r] + bg, 0.f));
                    }
                }
        }
        __syncthreads();
        if (wn == 0) {
            #pragma unroll
            for (int mi = 0; mi < MR; ++mi)
                #pragma unroll
                for (int ni = 0; ni < 4; ++ni) {
                    const int pc = ni * 16 + fr;
                    const float ba = bias[n0 + pc];
                    #pragma unroll
                    for (int r = 0; r < 4; ++r) {
                        const int row = wm * WROWS + mi * 16 + q * 4 + r;
                        const float a = acc[mi][ni][r] + ba;
                        const float o = a * h2f(xch[row * 64 + pc]);
                        Cq[(size_t)(m0 + row) * FFH + n0 + pc] = f2h(o);
                    }
                }
        }
    }
}

// ---------------------------------------------------------------------------
extern "C" void kernel_launch(void* const* d_in, const int* in_sizes, int n_in,
                              void* d_out, int out_size, void* d_ws, size_t ws_size,
                              hipStream_t stream)
{
    const float* hidden = (const float*)d_in[0];
    const float* qkv_w  = (const float*)d_in[2];
    const float* qkv_b  = (const float*)d_in[3];
    const float* out_w  = (const float*)d_in[4];
    const float* out_b  = (const float*)d_in[5];
    const float* key_w  = (const float*)d_in[7];
    const float* n1g    = (const float*)d_in[8];
    const float* n1b    = (const float*)d_in[9];
    const float* n2g    = (const float*)d_in[10];
    const float* n2b    = (const float*)d_in[11];
    const float* l1w    = (const float*)d_in[12];
    const float* l1b    = (const float*)d_in[13];
    const float* l2w    = (const float*)d_in[14];
    const float* l2b    = (const float*)d_in[15];
    float* out = (float*)d_out;
    char*  wsb = (char*)d_ws;

    const size_t MB = 1u << 20;
    unsigned short* h16    = (unsigned short*)wsb;               // 16 MB
    unsigned short* kv16   = (unsigned short*)(wsb + 16 * MB);   // 32 MB
    unsigned short* act16  = (unsigned short*)(wsb + 16 * MB);   // overlay
    unsigned short* vq     = (unsigned short*)(wsb + 48 * MB);   // 16 MB
    unsigned short* wkv_sw = (unsigned short*)(wsb + 64 * MB);   // 4 MB
    unsigned short* wo_sw  = (unsigned short*)(wsb + 68 * MB);   // 2 MB
    unsigned short* l1_sw  = (unsigned short*)(wsb + 70 * MB);   // 8 MB
    unsigned short* l2_sw  = (unsigned short*)(wsb + 78 * MB);   // 4 MB
    float*          gk     = (float*)(wsb + 82 * MB);            // 32 KB
    float*          pm     = (float*)(wsb + 83 * MB);            // 128 KB
    float*          pl     = (float*)(wsb + 83 * MB + 131072);
    float*          ps     = (float*)(wsb + 83 * MB + 262144);

    // 0. weights -> fp16 fragment-linear layout (coalesced reads)
    wcast_cl<<<4608, 256, 0, stream>>>(
        qkv_w + (size_t)DM * DM, out_w, l1w, l2w,
        wkv_sw, wo_sw, l1_sw, l2_sw);

    // 1. h1 = LN1(hidden) -> fp16
    ln_f16<<<M_TOT, 256, 0, stream>>>(hidden, n1g, n1b, h16);

    // 2. kv16 = fp16( h1 @ Wkv^T + b )  (ldc 2048), 512 blocks (2/CU even)
    fgemm5<false, 0, 256><<<dim3(16, 32), 256, 0, stream>>>(
        h16, wkv_sw, qkv_b + DM, nullptr, nullptr, kv16, 1024, 1024, 2048);

    // 3. global_key (partial + merge)
    attn_part<<<512, 256, 0, stream>>>(kv16, key_w, pm, pl, ps);
    attn_merge<<<128, 64, 0, stream>>>(pm, pl, ps, gk);

    // 4. vq = fp16(v * gk)
    vscale_f16<<<M_TOT, 256, 0, stream>>>(kv16, gk, vq);

    // 5. hidden2 = hidden + vq @ out_w^T + out_b -> d_out, 512 blocks
    fgemm5<false, 2, 128><<<dim3(8, 64), 256, 0, stream>>>(
        vq, wo_sw, out_b, hidden, out, nullptr, 1024, 1024, 1024);

    // 6. h2 = LN2(hidden2) -> fp16
    ln_f16<<<M_TOT, 256, 0, stream>>>(out, n2g, n2b, h16);

    // 7. act16 = fp16( (h2@W_a^T+b_a) * relu(h2@W_g^T+b_g) ), 1024 blocks
    fgemm5<true, 0, 256><<<dim3(32, 32), 256, 0, stream>>>(
        h16, l1_sw, l1b, nullptr, nullptr, act16, 1024, 1024, 0);

    // 8. out = hidden2 + act @ l2w^T + l2b (in-place residual), 512 blocks
    fgemm5<false, 2, 128><<<dim3(8, 64), 256, 0, stream>>>(
        act16, l2_sw, l2b, out, out, nullptr, 2048, 2048, 1024);
}